// Round 24
// baseline (815.867 us; speedup 1.0000x reference)
//
// r24 = r20 chassis + soft-tie averaging: queries whose rank-9/10 f32-d gap < 1.5e-6
// include BOTH candidates at half weight (robust to gold's unknown tie side).
#include <hip/hip_runtime.h>
#include <hip/hip_bf16.h>
#include <stdint.h>

#define NPTS 8192
#define NB 2

typedef unsigned int uint32;
typedef unsigned long long u64;
typedef unsigned short u16;
typedef short short8 __attribute__((ext_vector_type(8)));
typedef float f32x4 __attribute__((ext_vector_type(4)));

#define WB_IDX9  6291456u   // int [2][8192][12]: slots 0..9 idx, slot 10 = amb flag
#define WB_NORM  7077888u   // f32 [2][8192][32]
#define WB_WT    9175040u   // f32 [2][8192][160]  (10 slots x 16)
#define WB_PTS1  19660800u  // f32 [2][128][8192]
#define WB_PTS2  28049408u  // f32 [2][8192][128]
#define WB_L0BF  36438016u
#define WB_L0LO  37519360u
#define WB_L1BF  38600704u
#define WB_L1LO  39141376u
#define WB_W0BF  39682048u
#define WB_W0LO  39714816u
#define WB_W1BF  39747584u
#define WB_W1LO  39763968u
#define WB_BN    39780352u
// u64 keys [2][8192][8][10] = 10485760 B overlay pts1/pts2 (dead until conv0)
#define WB_KEYS  19660800u

__device__ __forceinline__ u16 f2bf(float x) {
  uint32 u = __float_as_uint(x);
  u += 0x7fffu + ((u >> 16) & 1u);
  return (u16)(u >> 16);
}
__device__ __forceinline__ float bf2f(u16 h) { return __uint_as_float((uint32)h << 16); }
__device__ __forceinline__ float lrelu(float x) { return x > 0.f ? x : 0.1f * x; }
__device__ __forceinline__ uint32 ford(float d) {
  uint32 u = __float_as_uint(d);
  return (u & 0x80000000u) ? ~u : (u | 0x80000000u);
}
__device__ __forceinline__ float unford(uint32 o) {
  return (o & 0x80000000u) ? __uint_as_float(o & 0x7FFFFFFFu) : __uint_as_float(~o);
}
// strict f32, numpy op order
__device__ __forceinline__ float sq3n(float x, float y, float z) {
  return __fadd_rn(__fadd_rn(__fmul_rn(x, x), __fmul_rn(y, y)), __fmul_rn(z, z));
}

__global__ void k_prep(const float* __restrict__ L0, const float* __restrict__ L1,
                       const float* __restrict__ W0, const float* __restrict__ W1,
                       const float* __restrict__ lb0, const float* __restrict__ g0,
                       const float* __restrict__ bb0, const float* __restrict__ m0,
                       const float* __restrict__ v0,
                       const float* __restrict__ lb1, const float* __restrict__ g1,
                       const float* __restrict__ bb1, const float* __restrict__ m1,
                       const float* __restrict__ v1,
                       u16* __restrict__ L0bf, u16* __restrict__ L0lo,
                       u16* __restrict__ L1bf, u16* __restrict__ L1lo,
                       u16* __restrict__ W0bf, u16* __restrict__ W0lo,
                       u16* __restrict__ W1bf, u16* __restrict__ W1lo,
                       float* __restrict__ bn) {
  int i = blockIdx.x * 256 + threadIdx.x;
  if (i < 128 * 4224) {
    int o = i / 4224, kk = i % 4224;
    float w = kk < 4192 ? L0[o * 4192 + kk] : 0.f;
    u16 h = f2bf(w);
    L0bf[i] = h;
    L0lo[i] = f2bf(w - bf2f(h));
    return;
  }
  i -= 128 * 4224;
  if (i < 128 * 2112) {
    int o = i / 2112, kk = i % 2112;
    float w = kk < 2096 ? L1[o * 2096 + kk] : 0.f;
    u16 h = f2bf(w);
    L1bf[i] = h;
    L1lo[i] = f2bf(w - bf2f(h));
    return;
  }
  i -= 128 * 2112;
  if (i < 16384) {
    float w = W0[i];
    u16 h = f2bf(w);
    W0bf[i] = h;
    W0lo[i] = f2bf(w - bf2f(h));
    return;
  }
  i -= 16384;
  if (i < 8192) {
    float w = W1[i];
    u16 h = f2bf(w);
    W1bf[i] = h;
    W1lo[i] = f2bf(w - bf2f(h));
    return;
  }
  i -= 8192;
  if (i < 256) {
    int layer = i >> 7, o = i & 127;
    if (layer == 0) {
      float s = g0[o] / sqrtf(v0[o] + 1e-5f);
      bn[o] = s;
      bn[128 + o] = (lb0[o] - m0[o]) * s + bb0[o];
    } else {
      float s = g1[o] / sqrtf(v1[o] + 1e-5f);
      bn[256 + o] = s;
      bn[384 + o] = (lb1[o] - m1[o]) * s + bb1[o];
    }
  }
}

// KNN pass 1: per-1024-chunk EXACT top-10 by strict-f32 np-order distance
__global__ __launch_bounds__(256, 2) void k_knn(const float* __restrict__ xyz,
                                                u64* __restrict__ keys) {
  __shared__ float4 cand[1024];
  int bid = blockIdx.x;
  int b = bid >> 8;
  int qt = (bid >> 3) & 31;
  int ch = bid & 7;
  const float* xb = xyz + b * 3 * NPTS;
  int c0 = ch * 1024;
  for (int t = threadIdx.x; t < 1024; t += 256) {
    int j = c0 + t;
    float x = xb[j], y = xb[NPTS + j], z = xb[2 * NPTS + j];
    cand[t] = make_float4(x, y, z, sq3n(x, y, z));
  }
  __syncthreads();
  int q = qt * 256 + threadIdx.x;
  float qx = xb[q], qy = xb[NPTS + q], qz = xb[2 * NPTS + q];
  float sqq = sq3n(qx, qy, qz);
  u64 s[10];
#pragma unroll
  for (int i = 0; i < 10; i++) s[i] = ~0ull;
#pragma unroll 2
  for (int j = 0; j < 1024; j++) {
    float4 c = cand[j];
    float dot = __fadd_rn(__fadd_rn(__fmul_rn(qx, c.x), __fmul_rn(qy, c.y)),
                          __fmul_rn(qz, c.z));
    float d = __fsub_rn(__fadd_rn(sqq, c.w), __fmul_rn(2.0f, dot));
    u64 key = ((u64)ford(d) << 13) | (uint32)(c0 + j);
    if (key < s[9]) {
      s[9] = key;
#pragma unroll
      for (int t = 9; t > 0; --t) {
        u64 a = s[t - 1], bq = s[t];
        s[t - 1] = a < bq ? a : bq;
        s[t] = a < bq ? bq : a;
      }
    }
  }
  u64* dst = keys + ((size_t)(b * NPTS + q) * 8 + ch) * 10;
#pragma unroll
  for (int i = 0; i < 10; i++) dst[i] = s[i];
}

// KNN pass 2: merge 8 chunk top-10s -> global top-10; flag rank-9/10 near-tie
__global__ __launch_bounds__(256) void k_merge(const u64* __restrict__ keys,
                                               int* __restrict__ idx9) {
  int t = blockIdx.x * 256 + threadIdx.x;
  const u64* src = keys + (size_t)t * 80;
  u64 s[10];
#pragma unroll
  for (int i = 0; i < 10; i++) s[i] = ~0ull;
  for (int g = 0; g < 8; g++) {
#pragma unroll
    for (int i = 0; i < 10; i++) {
      u64 k = src[g * 10 + i];
      if (k >= s[9]) break;
      s[9] = k;
#pragma unroll
      for (int j = 9; j > 0; --j) {
        u64 a = s[j - 1], bq = s[j];
        s[j - 1] = a < bq ? a : bq;
        s[j] = a < bq ? bq : a;
      }
    }
  }
  float d8 = unford((uint32)(s[8] >> 13));
  float d9 = unford((uint32)(s[9] >> 13));
  int amb = (d9 - d8) < 1.5e-6f ? 1 : 0;
  int* dst = idx9 + (size_t)t * 12;
#pragma unroll
  for (int i = 0; i < 10; i++) dst[i] = (int)(s[i] & 8191u);
  dst[10] = amb;
}

// WeightNet for 10 slots; slot weights: k<8 ->1, k=8 -> amb?0.5:1, k=9 -> amb?0.5:0
__global__ __launch_bounds__(256) void k_wn(const float* __restrict__ xyz,
                                            const int* __restrict__ idx9,
                                            const float* __restrict__ w0, const float* __restrict__ b0,
                                            const float* __restrict__ w1, const float* __restrict__ b1,
                                            const float* __restrict__ w2, const float* __restrict__ b2,
                                            float* __restrict__ norm_ws, float* __restrict__ wt_ws) {
  __shared__ float sw0[24], sb0[8], sw1[64], sb1[8], sw2[128], sb2[16];
  int tid = threadIdx.x;
  if (tid < 24) sw0[tid] = w0[tid];
  if (tid < 8) { sb0[tid] = b0[tid]; sb1[tid] = b1[tid]; }
  if (tid < 64) sw1[tid] = w1[tid];
  if (tid < 128) sw2[tid] = w2[tid];
  if (tid < 16) sb2[tid] = b2[tid];
  __syncthreads();
  int t = blockIdx.x * 256 + tid;
  if (t >= NB * NPTS * 10) return;
  int b = t / (NPTS * 10);
  int r = t % (NPTS * 10);
  int n = r / 10, k = r % 10;
  const float* xb = xyz + b * 3 * NPTS;
  const int* row = idx9 + (size_t)(b * NPTS + n) * 12;
  int ni = row[k];
  int amb = row[10];
  float scale = (k < 8) ? 1.f : (k == 8 ? (amb ? 0.5f : 1.f) : (amb ? 0.5f : 0.f));
  float nx = xb[ni] - xb[n];
  float ny = xb[NPTS + ni] - xb[NPTS + n];
  float nz = xb[2 * NPTS + ni] - xb[2 * NPTS + n];
  float* np = norm_ws + (size_t)(b * NPTS + n) * 32 + k * 3;
  np[0] = nx; np[1] = ny; np[2] = nz;
  float h0[8], h1[8];
#pragma unroll
  for (int o = 0; o < 8; o++) {
    float s = fmaf(sw0[o * 3], nx, fmaf(sw0[o * 3 + 1], ny, fmaf(sw0[o * 3 + 2], nz, sb0[o])));
    h0[o] = fmaxf(s, 0.f);
  }
#pragma unroll
  for (int o = 0; o < 8; o++) {
    float s = sb1[o];
#pragma unroll
    for (int i = 0; i < 8; i++) s = fmaf(sw1[o * 8 + i], h0[i], s);
    h1[o] = fmaxf(s, 0.f);
  }
  float* wp = wt_ws + (size_t)(b * NPTS + n) * 160 + k * 16;
#pragma unroll
  for (int o = 0; o < 16; o++) {
    float s = sb2[o];
#pragma unroll
    for (int i = 0; i < 8; i++) s = fmaf(sw2[o * 8 + i], h1[i], s);
    wp[o] = fmaxf(s, 0.f) * scale;
  }
}

// pointconv over 10 weighted slots; split-bf16 MFMA; BN+leaky
// LDS: idx 1280 + union(gf 5120 + Ah/Al 9216 + Bh/Bl 36864 = 51200, yt 16384) = 52480 B
template <int LAYER>
__global__ __launch_bounds__(256, 2) void k_conv(
    const float* __restrict__ feats, const float* __restrict__ cost,
    const float* __restrict__ flow, const float* __restrict__ pts1cm,
    const float* __restrict__ norm_ws, const float* __restrict__ wt_ws,
    const int* __restrict__ idx9, const u16* __restrict__ Lbf,
    const u16* __restrict__ Llo, const float* __restrict__ bn,
    float* __restrict__ outp) {
  constexpr int NCH = (LAYER == 0) ? 66 : 33;
  constexpr int CC = (LAYER == 0) ? 262 : 131;
  constexpr int KP = (LAYER == 0) ? 4224 : 2112;
  __shared__ int idx_s[32][10];
  __shared__ union {
    struct {
      float gf[32][40];
      u16 Ah[32][72]; u16 Al[32][72];
      u16 Bh[128][72]; u16 Bl[128][72];
    } ph;
    float yt[32][128];
  } u;
  int tid = threadIdx.x;
  int bid = blockIdx.x;
  int b = bid >> 8, n0 = (bid & 255) * 32;
  for (int t = tid; t < 320; t += 256)
    idx_s[t / 10][t % 10] = idx9[(size_t)(b * NPTS + n0 + t / 10) * 12 + t % 10];
  int p_a = tid >> 3;
  int w0i = (tid & 7) * 2;
  float wr0[10], wr1[10];
  {
    const float* wp = wt_ws + (size_t)(b * NPTS + n0 + p_a) * 160 + w0i;
#pragma unroll
    for (int k = 0; k < 10; k++) {
      float2 v = *(const float2*)(wp + k * 16);
      wr0[k] = v.x; wr1[k] = v.y;
    }
  }
  __syncthreads();
  int lane = tid & 63, wv = tid >> 6;
  int pg = wv >> 1, oh = wv & 1;
  f32x4 acc0 = {0.f, 0.f, 0.f, 0.f}, acc1 = acc0, acc2 = acc0, acc3 = acc0;

  for (int chq = 0; chq < NCH; chq++) {
    int c0 = chq * 4;
    for (int v = tid; v < 1280; v += 256) {
      int p = v / 40, r = v % 40, k = r >> 2, cl = r & 3;
      int c = c0 + cl;
      float val = 0.f;
      int ni = idx_s[p][k];
      if (c < 3)
        val = norm_ws[(size_t)(b * NPTS + n0 + p) * 32 + k * 3 + c];
      else if (c < CC) {
        int cc = c - 3;
        if (LAYER == 0) {
          if (cc < 128) val = feats[(size_t)(b * 128 + cc) * NPTS + ni];
          else if (cc < 256) val = cost[(size_t)(b * 128 + cc - 128) * NPTS + ni];
          else val = flow[(size_t)(b * 3 + cc - 256) * NPTS + ni];
        } else {
          val = pts1cm[(size_t)(b * 128 + cc) * NPTS + ni];
        }
      }
      u.ph.gf[p][r] = val;
    }
    __syncthreads();
#pragma unroll
    for (int cl = 0; cl < 4; cl++) {
      float a0 = 0.f, a1 = 0.f;
#pragma unroll
      for (int k = 0; k < 10; k++) {
        float g = u.ph.gf[p_a][k * 4 + cl];
        a0 = fmaf(g, wr0[k], a0);
        a1 = fmaf(g, wr1[k], a1);
      }
      u16 h0 = f2bf(a0);
      u16 l0 = f2bf(a0 - bf2f(h0));
      u16 h1 = f2bf(a1);
      u16 l1 = f2bf(a1 - bf2f(h1));
      *(uint32*)&u.ph.Ah[p_a][cl * 16 + w0i] = (uint32)h0 | ((uint32)h1 << 16);
      *(uint32*)&u.ph.Al[p_a][cl * 16 + w0i] = (uint32)l0 | ((uint32)l1 << 16);
    }
    {
      int o = tid >> 1, half = tid & 1;
      const uint4* s4 = (const uint4*)(Lbf + (size_t)o * KP + c0 * 16 + half * 32);
      const uint4* s4l = (const uint4*)(Llo + (size_t)o * KP + c0 * 16 + half * 32);
      uint4* d4 = (uint4*)&u.ph.Bh[o][half * 32];
      uint4* d4l = (uint4*)&u.ph.Bl[o][half * 32];
      d4[0] = s4[0]; d4[1] = s4[1]; d4[2] = s4[2]; d4[3] = s4[3];
      d4l[0] = s4l[0]; d4l[1] = s4l[1]; d4l[2] = s4l[2]; d4l[3] = s4l[3];
    }
    __syncthreads();
    {
      int arow = pg * 16 + (lane & 15);
      int koff = (lane >> 4) * 8;
      int brow = (lane & 15);
#pragma unroll
      for (int ks = 0; ks < 2; ks++) {
        short8 ah = *(const short8*)&u.ph.Ah[arow][ks * 32 + koff];
        short8 al = *(const short8*)&u.ph.Al[arow][ks * 32 + koff];
        short8 b0v = *(const short8*)&u.ph.Bh[(oh * 4 + 0) * 16 + brow][ks * 32 + koff];
        short8 b0l = *(const short8*)&u.ph.Bl[(oh * 4 + 0) * 16 + brow][ks * 32 + koff];
        acc0 = __builtin_amdgcn_mfma_f32_16x16x32_bf16(ah, b0v, acc0, 0, 0, 0);
        acc0 = __builtin_amdgcn_mfma_f32_16x16x32_bf16(al, b0v, acc0, 0, 0, 0);
        acc0 = __builtin_amdgcn_mfma_f32_16x16x32_bf16(ah, b0l, acc0, 0, 0, 0);
        short8 b1v = *(const short8*)&u.ph.Bh[(oh * 4 + 1) * 16 + brow][ks * 32 + koff];
        short8 b1l = *(const short8*)&u.ph.Bl[(oh * 4 + 1) * 16 + brow][ks * 32 + koff];
        acc1 = __builtin_amdgcn_mfma_f32_16x16x32_bf16(ah, b1v, acc1, 0, 0, 0);
        acc1 = __builtin_amdgcn_mfma_f32_16x16x32_bf16(al, b1v, acc1, 0, 0, 0);
        acc1 = __builtin_amdgcn_mfma_f32_16x16x32_bf16(ah, b1l, acc1, 0, 0, 0);
        short8 b2v = *(const short8*)&u.ph.Bh[(oh * 4 + 2) * 16 + brow][ks * 32 + koff];
        short8 b2l = *(const short8*)&u.ph.Bl[(oh * 4 + 2) * 16 + brow][ks * 32 + koff];
        acc2 = __builtin_amdgcn_mfma_f32_16x16x32_bf16(ah, b2v, acc2, 0, 0, 0);
        acc2 = __builtin_amdgcn_mfma_f32_16x16x32_bf16(al, b2v, acc2, 0, 0, 0);
        acc2 = __builtin_amdgcn_mfma_f32_16x16x32_bf16(ah, b2l, acc2, 0, 0, 0);
        short8 b3v = *(const short8*)&u.ph.Bh[(oh * 4 + 3) * 16 + brow][ks * 32 + koff];
        short8 b3l = *(const short8*)&u.ph.Bl[(oh * 4 + 3) * 16 + brow][ks * 32 + koff];
        acc3 = __builtin_amdgcn_mfma_f32_16x16x32_bf16(ah, b3v, acc3, 0, 0, 0);
        acc3 = __builtin_amdgcn_mfma_f32_16x16x32_bf16(al, b3v, acc3, 0, 0, 0);
        acc3 = __builtin_amdgcn_mfma_f32_16x16x32_bf16(ah, b3l, acc3, 0, 0, 0);
      }
    }
    __syncthreads();
  }
  const float* sc = bn;
  const float* sh = bn + 128;
  int prow = pg * 16 + (lane >> 4) * 4;
  if (LAYER == 0) {
#pragma unroll
    for (int t = 0; t < 4; t++) {
      int o = (oh * 4 + t) * 16 + (lane & 15);
      float s = sc[o], h = sh[o];
      f32x4 a = (t == 0) ? acc0 : (t == 1) ? acc1 : (t == 2) ? acc2 : acc3;
#pragma unroll
      for (int r = 0; r < 4; r++) u.yt[prow + r][o] = lrelu(fmaf(a[r], s, h));
    }
    __syncthreads();
    int o = tid >> 1, pq = (tid & 1) * 16;
    float* dst = outp + (size_t)(b * 128 + o) * NPTS + n0 + pq;
#pragma unroll
    for (int i = 0; i < 16; i += 4) {
      float4 vv = make_float4(u.yt[pq + i][o], u.yt[pq + i + 1][o],
                              u.yt[pq + i + 2][o], u.yt[pq + i + 3][o]);
      *(float4*)(dst + i) = vv;
    }
  } else {
#pragma unroll
    for (int t = 0; t < 4; t++) {
      int o = (oh * 4 + t) * 16 + (lane & 15);
      float s = sc[o], h = sh[o];
      f32x4 a = (t == 0) ? acc0 : (t == 1) ? acc1 : (t == 2) ? acc2 : acc3;
#pragma unroll
      for (int r = 0; r < 4; r++)
        outp[(size_t)(b * NPTS + n0 + prow + r) * 128 + o] = lrelu(fmaf(a[r], s, h));
    }
  }
}

__global__ __launch_bounds__(256) void k_mlp(const float* __restrict__ pts2,
                                             const u16* __restrict__ W0bf,
                                             const u16* __restrict__ W0lo,
                                             const u16* __restrict__ W1bf,
                                             const u16* __restrict__ W1lo,
                                             const float* __restrict__ b0,
                                             const float* __restrict__ b1,
                                             const float* __restrict__ fcw,
                                             const float* __restrict__ fcb,
                                             float* __restrict__ out0,
                                             float* __restrict__ out1) {
  __shared__ u16 A_s[32][136];
  __shared__ u16 Al_s[32][136];
  __shared__ u16 W_s[128][136];
  __shared__ float yt[32][68];
  int tid = threadIdx.x;
  int b = blockIdx.x >> 8, n0 = (blockIdx.x & 255) * 32;
  {
    int p = tid >> 3, cq = (tid & 7) * 16;
    const float* src = pts2 + (size_t)(b * NPTS + n0 + p) * 128 + cq;
#pragma unroll
    for (int i = 0; i < 16; i++) {
      float x = src[i];
      u16 h = f2bf(x);
      A_s[p][cq + i] = h;
      Al_s[p][cq + i] = f2bf(x - bf2f(h));
    }
  }
  {
    int o = tid >> 1, half = tid & 1;
    const uint4* s4 = (const uint4*)(W0bf + o * 128 + half * 64);
    uint4* d4 = (uint4*)&W_s[o][half * 64];
#pragma unroll
    for (int i = 0; i < 8; i++) d4[i] = s4[i];
  }
  __syncthreads();
  int lane = tid & 63, wv = tid >> 6, pg = wv >> 1, oh = wv & 1;
  int arow = pg * 16 + (lane & 15), koff = (lane >> 4) * 8, brow = lane & 15;
  int prow = pg * 16 + (lane >> 4) * 4;
  f32x4 y0a = {0.f, 0.f, 0.f, 0.f}, y0b = y0a, y0c = y0a, y0d = y0a;
#pragma unroll
  for (int ks = 0; ks < 4; ks++) {
    short8 af = *(const short8*)&A_s[arow][ks * 32 + koff];
    short8 afl = *(const short8*)&Al_s[arow][ks * 32 + koff];
    short8 w0v = *(const short8*)&W_s[(oh * 4 + 0) * 16 + brow][ks * 32 + koff];
    y0a = __builtin_amdgcn_mfma_f32_16x16x32_bf16(af, w0v, y0a, 0, 0, 0);
    y0a = __builtin_amdgcn_mfma_f32_16x16x32_bf16(afl, w0v, y0a, 0, 0, 0);
    short8 w1v = *(const short8*)&W_s[(oh * 4 + 1) * 16 + brow][ks * 32 + koff];
    y0b = __builtin_amdgcn_mfma_f32_16x16x32_bf16(af, w1v, y0b, 0, 0, 0);
    y0b = __builtin_amdgcn_mfma_f32_16x16x32_bf16(afl, w1v, y0b, 0, 0, 0);
    short8 w2v = *(const short8*)&W_s[(oh * 4 + 2) * 16 + brow][ks * 32 + koff];
    y0c = __builtin_amdgcn_mfma_f32_16x16x32_bf16(af, w2v, y0c, 0, 0, 0);
    y0c = __builtin_amdgcn_mfma_f32_16x16x32_bf16(afl, w2v, y0c, 0, 0, 0);
    short8 w3v = *(const short8*)&W_s[(oh * 4 + 3) * 16 + brow][ks * 32 + koff];
    y0d = __builtin_amdgcn_mfma_f32_16x16x32_bf16(af, w3v, y0d, 0, 0, 0);
    y0d = __builtin_amdgcn_mfma_f32_16x16x32_bf16(afl, w3v, y0d, 0, 0, 0);
  }
  __syncthreads();
  {
    int o = tid >> 1, half = tid & 1;
    const uint4* s4 = (const uint4*)(W0lo + o * 128 + half * 64);
    uint4* d4 = (uint4*)&W_s[o][half * 64];
#pragma unroll
    for (int i = 0; i < 8; i++) d4[i] = s4[i];
  }
  __syncthreads();
#pragma unroll
  for (int ks = 0; ks < 4; ks++) {
    short8 af = *(const short8*)&A_s[arow][ks * 32 + koff];
    short8 w0v = *(const short8*)&W_s[(oh * 4 + 0) * 16 + brow][ks * 32 + koff];
    y0a = __builtin_amdgcn_mfma_f32_16x16x32_bf16(af, w0v, y0a, 0, 0, 0);
    short8 w1v = *(const short8*)&W_s[(oh * 4 + 1) * 16 + brow][ks * 32 + koff];
    y0b = __builtin_amdgcn_mfma_f32_16x16x32_bf16(af, w1v, y0b, 0, 0, 0);
    short8 w2v = *(const short8*)&W_s[(oh * 4 + 2) * 16 + brow][ks * 32 + koff];
    y0c = __builtin_amdgcn_mfma_f32_16x16x32_bf16(af, w2v, y0c, 0, 0, 0);
    short8 w3v = *(const short8*)&W_s[(oh * 4 + 3) * 16 + brow][ks * 32 + koff];
    y0d = __builtin_amdgcn_mfma_f32_16x16x32_bf16(af, w3v, y0d, 0, 0, 0);
  }
  __syncthreads();
#pragma unroll
  for (int t = 0; t < 4; t++) {
    int o = (oh * 4 + t) * 16 + (lane & 15);
    float bias = b0[o];
    f32x4 a = (t == 0) ? y0a : (t == 1) ? y0b : (t == 2) ? y0c : y0d;
#pragma unroll
    for (int r = 0; r < 4; r++) {
      float x = lrelu(a[r] + bias);
      u16 h = f2bf(x);
      A_s[prow + r][o] = h;
      Al_s[prow + r][o] = f2bf(x - bf2f(h));
    }
  }
  {
    int o = tid >> 2, qq = (tid & 3) * 32;
    const uint4* s4 = (const uint4*)(W1bf + o * 128 + qq);
    uint4* d4 = (uint4*)&W_s[o][qq];
#pragma unroll
    for (int i = 0; i < 4; i++) d4[i] = s4[i];
  }
  __syncthreads();
  f32x4 y1a = {0.f, 0.f, 0.f, 0.f}, y1b = y1a;
#pragma unroll
  for (int ks = 0; ks < 4; ks++) {
    short8 af = *(const short8*)&A_s[arow][ks * 32 + koff];
    short8 afl = *(const short8*)&Al_s[arow][ks * 32 + koff];
    short8 w0v = *(const short8*)&W_s[(oh * 2 + 0) * 16 + brow][ks * 32 + koff];
    y1a = __builtin_amdgcn_mfma_f32_16x16x32_bf16(af, w0v, y1a, 0, 0, 0);
    y1a = __builtin_amdgcn_mfma_f32_16x16x32_bf16(afl, w0v, y1a, 0, 0, 0);
    short8 w1v = *(const short8*)&W_s[(oh * 2 + 1) * 16 + brow][ks * 32 + koff];
    y1b = __builtin_amdgcn_mfma_f32_16x16x32_bf16(af, w1v, y1b, 0, 0, 0);
    y1b = __builtin_amdgcn_mfma_f32_16x16x32_bf16(afl, w1v, y1b, 0, 0, 0);
  }
  __syncthreads();
  {
    int o = tid >> 2, qq = (tid & 3) * 32;
    const uint4* s4 = (const uint4*)(W1lo + o * 128 + qq);
    uint4* d4 = (uint4*)&W_s[o][qq];
#pragma unroll
    for (int i = 0; i < 4; i++) d4[i] = s4[i];
  }
  __syncthreads();
#pragma unroll
  for (int ks = 0; ks < 4; ks++) {
    short8 af = *(const short8*)&A_s[arow][ks * 32 + koff];
    short8 w0v = *(const short8*)&W_s[(oh * 2 + 0) * 16 + brow][ks * 32 + koff];
    y1a = __builtin_amdgcn_mfma_f32_16x16x32_bf16(af, w0v, y1a, 0, 0, 0);
    short8 w1v = *(const short8*)&W_s[(oh * 2 + 1) * 16 + brow][ks * 32 + koff];
    y1b = __builtin_amdgcn_mfma_f32_16x16x32_bf16(af, w1v, y1b, 0, 0, 0);
  }
#pragma unroll
  for (int t = 0; t < 2; t++) {
    int o = (oh * 2 + t) * 16 + (lane & 15);
    float bias = b1[o];
    f32x4 a = t ? y1b : y1a;
#pragma unroll
    for (int r = 0; r < 4; r++) yt[prow + r][o] = lrelu(a[r] + bias);
  }
  __syncthreads();
  {
    int o = tid >> 2, pq = (tid & 3) * 8;
    float* dst = out0 + (size_t)(b * 64 + o) * NPTS + n0 + pq;
#pragma unroll
    for (int i = 0; i < 8; i += 4) {
      float4 vv = make_float4(yt[pq + i][o], yt[pq + i + 1][o],
                              yt[pq + i + 2][o], yt[pq + i + 3][o]);
      *(float4*)(dst + i) = vv;
    }
  }
  if (tid < 96) {
    int p = tid / 3, j = tid % 3;
    float s = fcb[j];
#pragma unroll
    for (int c = 0; c < 64; c++) s = fmaf(fcw[j * 64 + c], yt[p][c], s);
    s = fminf(fmaxf(s, -200.f), 200.f);
    out1[(size_t)(b * 3 + j) * NPTS + n0 + p] = s;
  }
}

extern "C" void kernel_launch(void* const* d_in, const int* in_sizes, int n_in,
                              void* d_out, int out_size, void* d_ws, size_t ws_size,
                              hipStream_t stream) {
  const float* xyz = (const float*)d_in[0];
  const float* feats = (const float*)d_in[1];
  const float* cost = (const float*)d_in[2];
  const float* flow = (const float*)d_in[3];
  const float* p0w0 = (const float*)d_in[4];
  const float* p0b0 = (const float*)d_in[5];
  const float* p0w1 = (const float*)d_in[6];
  const float* p0b1 = (const float*)d_in[7];
  const float* p0w2 = (const float*)d_in[8];
  const float* p0b2 = (const float*)d_in[9];
  const float* p0lw = (const float*)d_in[10];
  const float* p0lb = (const float*)d_in[11];
  const float* p0g = (const float*)d_in[12];
  const float* p0bb = (const float*)d_in[13];
  const float* p0m = (const float*)d_in[14];
  const float* p0v = (const float*)d_in[15];
  const float* p1w0 = (const float*)d_in[16];
  const float* p1b0 = (const float*)d_in[17];
  const float* p1w1 = (const float*)d_in[18];
  const float* p1b1 = (const float*)d_in[19];
  const float* p1w2 = (const float*)d_in[20];
  const float* p1b2 = (const float*)d_in[21];
  const float* p1lw = (const float*)d_in[22];
  const float* p1lb = (const float*)d_in[23];
  const float* p1g = (const float*)d_in[24];
  const float* p1bb = (const float*)d_in[25];
  const float* p1m = (const float*)d_in[26];
  const float* p1v = (const float*)d_in[27];
  const float* m0w = (const float*)d_in[28];
  const float* m0b = (const float*)d_in[29];
  const float* m1w = (const float*)d_in[30];
  const float* m1b = (const float*)d_in[31];
  const float* fcw = (const float*)d_in[32];
  const float* fcb = (const float*)d_in[33];

  char* ws = (char*)d_ws;
  u64* keys = (u64*)(ws + WB_KEYS);
  int* idx9 = (int*)(ws + WB_IDX9);
  float* norm_ws = (float*)(ws + WB_NORM);
  float* wt_ws = (float*)(ws + WB_WT);
  float* pts1 = (float*)(ws + WB_PTS1);
  float* pts2 = (float*)(ws + WB_PTS2);
  u16* L0bf = (u16*)(ws + WB_L0BF);
  u16* L0lo = (u16*)(ws + WB_L0LO);
  u16* L1bf = (u16*)(ws + WB_L1BF);
  u16* L1lo = (u16*)(ws + WB_L1LO);
  u16* W0bf = (u16*)(ws + WB_W0BF);
  u16* W0lo = (u16*)(ws + WB_W0LO);
  u16* W1bf = (u16*)(ws + WB_W1BF);
  u16* W1lo = (u16*)(ws + WB_W1LO);
  float* bn = (float*)(ws + WB_BN);

  k_knn<<<512, 256, 0, stream>>>(xyz, keys);
  k_merge<<<64, 256, 0, stream>>>(keys, idx9);
  k_prep<<<3265, 256, 0, stream>>>(p0lw, p1lw, m0w, m1w, p0lb, p0g, p0bb, p0m, p0v,
                                   p1lb, p1g, p1bb, p1m, p1v,
                                   L0bf, L0lo, L1bf, L1lo, W0bf, W0lo, W1bf, W1lo, bn);
  k_wn<<<640, 256, 0, stream>>>(xyz, idx9, p0w0, p0b0, p0w1, p0b1, p0w2, p0b2, norm_ws, wt_ws);
  k_conv<0><<<512, 256, 0, stream>>>(feats, cost, flow, nullptr, norm_ws, wt_ws, idx9,
                                     L0bf, L0lo, bn, pts1);
  k_wn<<<640, 256, 0, stream>>>(xyz, idx9, p1w0, p1b0, p1w1, p1b1, p1w2, p1b2, norm_ws, wt_ws);
  k_conv<1><<<512, 256, 0, stream>>>(feats, cost, flow, pts1, norm_ws, wt_ws, idx9,
                                     L1bf, L1lo, bn + 256, pts2);
  k_mlp<<<512, 256, 0, stream>>>(pts2, W0bf, W0lo, W1bf, W1lo, m0b, m1b, fcw, fcb,
                                 (float*)d_out, (float*)d_out + (size_t)2 * 64 * NPTS);
}